// Round 1
// baseline (44.680 us; speedup 1.0000x reference)
//
#include <hip/hip_runtime.h>

#define HM_H 256
#define HM_W 256
#define MAP_ELEMS (HM_H * HM_W)     // 65536
#define BLOCK 1024
#define V4_PER_MAP (MAP_ELEMS / 4)  // 16384
#define ITERS (V4_PER_MAP / BLOCK)  // 16

__global__ __launch_bounds__(BLOCK) void heatmap_fit_kernel(
    const float* __restrict__ x, float* __restrict__ out)
{
    const int map = blockIdx.x;  // b*K + k
    const size_t base = (size_t)map * MAP_ELEMS;
    const float4* __restrict__ x4 = reinterpret_cast<const float4*>(x + base);
    float4* __restrict__ o4 = reinterpret_cast<float4*>(out + base);

    const int tid = threadIdx.x;

    // ---------- Phase 1: reduce  S = sum x,  SR = sum x*row,  SC = sum x*col
    float s = 0.f, sr = 0.f, sc = 0.f;
#pragma unroll
    for (int i = 0; i < ITERS; ++i) {
        const int j = i * BLOCK + tid;      // float4 index within map
        const float4 v = x4[j];
        const int e = j * 4;                // element index
        const float row = (float)(e >> 8);  // e / 256
        const float c0  = (float)(e & 255); // e % 256
        const float sum4 = (v.x + v.y) + (v.z + v.w);
        s  += sum4;
        sr += sum4 * row;
        // x*col for the 4 lanes: c0*sum4 + (0*v.x + 1*v.y + 2*v.z + 3*v.w)
        sc += c0 * sum4 + (v.y + 2.f * v.z + 3.f * v.w);
    }

    // wave (64-lane) butterfly reduce
#pragma unroll
    for (int off = 32; off > 0; off >>= 1) {
        s  += __shfl_down(s,  off);
        sr += __shfl_down(sr, off);
        sc += __shfl_down(sc, off);
    }

    __shared__ float reds[BLOCK / 64][3];
    __shared__ float params[5];
    const int wave = tid >> 6;
    const int lane = tid & 63;
    if (lane == 0) {
        reds[wave][0] = s;
        reds[wave][1] = sr;
        reds[wave][2] = sc;
    }
    __syncthreads();

    if (tid == 0) {
        float S = 0.f, SR = 0.f, SC = 0.f;
#pragma unroll
        for (int w = 0; w < BLOCK / 64; ++w) {
            S += reds[w][0]; SR += reds[w][1]; SC += reds[w][2];
        }
        const float mu_x = SC / S;   // column-weighted center
        const float mu_y = SR / S;   // row-weighted center

        // closed-form unweighted grid moments
        const float EC  = (HM_W - 1) * 0.5f;                          // 127.5
        const float EC2 = (float)((HM_W - 1) * (2 * HM_W - 1)) / 6.f; // 21717.5
        const float ER  = (HM_H - 1) * 0.5f;
        const float ER2 = (float)((HM_H - 1) * (2 * HM_H - 1)) / 6.f;

        const float var_x = EC2 - 2.f * mu_x * EC + mu_x * mu_x;
        const float var_y = ER2 - 2.f * mu_y * ER + mu_y * mu_y;
        const float cov   = (EC - mu_x) * (ER - mu_y);
        const float det   = var_x * var_y - cov * cov;

        params[0] = mu_x;
        params[1] = mu_y;
        params[2] = var_y / det;   // a
        params[3] = -cov / det;    // b
        params[4] = var_x / det;   // c
    }
    __syncthreads();

    const float mu_x = params[0];
    const float mu_y = params[1];
    const float A  = params[2];
    const float Bv = params[3];
    const float C  = params[4];

    // ---------- Phase 2: write out = 1 / (1 + a*v0^2 + 2b*v0*v1 + c*v1^2)
    // quirk: v0 = row - mu_x, v1 = col - mu_y
#pragma unroll
    for (int i = 0; i < ITERS; ++i) {
        const int j = i * BLOCK + tid;
        const int e = j * 4;
        const float v0 = (float)(e >> 8) - mu_x;
        const float c0 = (float)(e & 255);
        const float t0 = A * v0 * v0;     // constant term in v1
        const float t1 = 2.f * Bv * v0;   // linear coeff in v1
        float4 o;
        {
            const float v1 = c0 - mu_y;
            o.x = 1.f / (1.f + fmaf(fmaf(C, v1, t1), v1, t0));
        }
        {
            const float v1 = c0 + 1.f - mu_y;
            o.y = 1.f / (1.f + fmaf(fmaf(C, v1, t1), v1, t0));
        }
        {
            const float v1 = c0 + 2.f - mu_y;
            o.z = 1.f / (1.f + fmaf(fmaf(C, v1, t1), v1, t0));
        }
        {
            const float v1 = c0 + 3.f - mu_y;
            o.w = 1.f / (1.f + fmaf(fmaf(C, v1, t1), v1, t0));
        }
        o4[j] = o;
    }
}

extern "C" void kernel_launch(void* const* d_in, const int* in_sizes, int n_in,
                              void* d_out, int out_size, void* d_ws, size_t ws_size,
                              hipStream_t stream) {
    const float* x = (const float*)d_in[0];
    float* out = (float*)d_out;
    const int n_maps = in_sizes[0] / MAP_ELEMS;  // 16*32 = 512
    heatmap_fit_kernel<<<n_maps, BLOCK, 0, stream>>>(x, out);
}